// Round 5
// baseline (347.716 us; speedup 1.0000x reference)
//
#include <hip/hip_runtime.h>
#include <hip/hip_fp16.h>

// GRU scan, segmented + chain-batched MFMA. History:
//   R5: LDS>80KB forces 1 block/CU; weights LDS-laundered (anti-remat). 36.2ms
//   R6: segment chain, warmup (contraction bit-snaps) -> 1.03ms
//   R7: in-lane gates, 1 barrier/step -> 557us (step cost unchanged)
//   R8: MFMA matvec (A = h replicated, B = W^T in AGPRs) -> 463us.
//       Step 2762cy; MFMA floor = 384 MFMA/CU x 4.85cy = 1862cy.
//   R9: C chains packed in A-rows; wall 256->101; gi_gemm f16-MFMA. 290us.
//       Step REGRESSED to 4920cy: 12 scalar gi loads/lane issued post-MFMA,
//       staging stride-13 still 8-way write-conflicted (5.46M), h-reads 4-way.
//   R10 (this):
//     a) gi split layout grz[row][u]{r,z}(4B)+gn[row][u](2B), same 53MB total:
//        DEC loads 12->8, ENC 6->4 per lane-step, grz 64B-coalesced/16 lanes;
//        issued at TOP of loop (T14), consumed at tail.
//     b) staging layout [j*NT+t]: consecutive lanes -> consecutive 16B,
//        conflict-free both directions (R9's stride-pad was the wrong fix).
//     c) DEC lower clamp dropped (negative idx reads encoder region legally;
//        hnew forced 0 while ic<0 -> bit-exact). Upper clamp = 1 v_min.
//     d) s_setprio(1) around MFMA cluster; ENC dup h-writes masked (g&1)==0.
//     e) gi_gemm v2: 1 block per M-tile loops 12 N-tiles; x staged ONCE.

typedef _Float16 h8 __attribute__((ext_vector_type(8)));
typedef float f32x4 __attribute__((ext_vector_type(4)));
union U4H8 { uint4 u; h8 h; };
union HU { unsigned int u; _Float16 v[2]; };
union SH { unsigned short s; _Float16 h; };

__device__ __forceinline__ float fast_sigmoid(float x) {
  return __builtin_amdgcn_rcpf(1.0f + __builtin_amdgcn_exp2f(x * -1.4426950408889634f));
}

constexpr int B = 128, T_IN = 240, T_OUT = 30, D = 128, H = 256, G = 768;
constexpr int L_ENC = B * T_IN;   // 30720
constexpr int L_DEC = B * T_OUT;  // 3840
constexpr int ROWS  = L_ENC + L_DEC;            // 34560
// ws layout: grz = f16[ROWS][256][2] (35,389,440 B) then gn = f16[ROWS][256]
// (17,694,720 B); total 53,084,160 B (same as before).
constexpr size_t GN_OFF = (size_t)ROWS * 512;   // f16 elements

constexpr int WARM   = 96;
constexpr int NBLK_E = 120;   // C=2 -> 240 point-chains (emit i=128m+127)
constexpr int NBLK_D = 96;    // C=8 -> 768 segments x SEG_D
constexpr int SEG_D  = 5;     // 768*5 = 3840
constexpr int NT = 512;
constexpr int CH = 12;        // uint4 per thread staged per round

// ---------------- K1: gi = x @ W_ih^T + b_ih, f16 MFMA, 12 N-tiles/block ---
// grid 540; block 256 = 4 waves; M-tile 64, N-tile 64, K=128. x staged once.
__global__ __launch_bounds__(256) void gi_gemm(
    const float* __restrict__ x,
    const float* __restrict__ Wih_e, const float* __restrict__ bih_e,
    const float* __restrict__ Wih_d, const float* __restrict__ bih_d,
    _Float16* __restrict__ gi)
{
  const int by = blockIdx.x;            // M-tile 0..539
  const bool enc = by < (L_ENC / 64);
  const int row0 = enc ? by * 64 : (by - L_ENC / 64) * 64;   // segment-local
  const int rbase = enc ? row0 : L_ENC + row0;               // global row
  const float* __restrict__ W  = enc ? Wih_e : Wih_d;
  const float* __restrict__ bi = enc ? bih_e : bih_d;
  _Float16* __restrict__ grz = gi;
  _Float16* __restrict__ gn  = gi + GN_OFF;

  __shared__ __align__(16) unsigned short xs[64][136];  // f16, +8 pad
  __shared__ __align__(16) unsigned short ws[64][136];
  const int t = threadIdx.x;
  const int wv = t >> 6, lane = t & 63;
  const int col = lane & 15, g = lane >> 4;

  // ---- stage x-tile once (f32 -> f16) ----
#pragma unroll
  for (int p = 0; p < 4; ++p) {
    int idx = p * 256 + t;              // 64 rows x 16 chunks
    int r  = idx >> 4;
    int c8 = (idx & 15) * 8;
    int i  = row0 + r;
    int bb = i & (B - 1);
    int tt = i >> 7;
    if (!enc) tt *= 8;                  // decoder reads x[:, ::8, :]
    const float* xp = x + (size_t)(bb * T_IN + tt) * D + c8;
    float4 f0 = *(const float4*)xp;
    float4 f1 = *(const float4*)(xp + 4);
    U4H8 pk;
    pk.h[0]=(_Float16)f0.x; pk.h[1]=(_Float16)f0.y; pk.h[2]=(_Float16)f0.z; pk.h[3]=(_Float16)f0.w;
    pk.h[4]=(_Float16)f1.x; pk.h[5]=(_Float16)f1.y; pk.h[6]=(_Float16)f1.z; pk.h[7]=(_Float16)f1.w;
    *(uint4*)&xs[r][c8] = pk.u;
  }
  __syncthreads();

  for (int jt = 0; jt < 12; ++jt) {
    // ---- stage W N-tile ----
#pragma unroll
    for (int p = 0; p < 4; ++p) {
      int idx = p * 256 + t;
      int r  = idx >> 4;
      int c8 = (idx & 15) * 8;
      const float* wp = W + (size_t)(jt * 64 + r) * D + c8;
      float4 q0 = *(const float4*)wp;
      float4 q1 = *(const float4*)(wp + 4);
      U4H8 qk;
      qk.h[0]=(_Float16)q0.x; qk.h[1]=(_Float16)q0.y; qk.h[2]=(_Float16)q0.z; qk.h[3]=(_Float16)q0.w;
      qk.h[4]=(_Float16)q1.x; qk.h[5]=(_Float16)q1.y; qk.h[6]=(_Float16)q1.z; qk.h[7]=(_Float16)q1.w;
      *(uint4*)&ws[r][c8] = qk.u;
    }
    __syncthreads();

    f32x4 acc[4];
#pragma unroll
    for (int nt = 0; nt < 4; ++nt) acc[nt] = (f32x4){0.f, 0.f, 0.f, 0.f};
#pragma unroll
    for (int kt = 0; kt < 4; ++kt) {
      U4H8 av; av.u = *(const uint4*)&xs[wv * 16 + col][kt * 32 + g * 8];
#pragma unroll
      for (int nt = 0; nt < 4; ++nt) {
        U4H8 bv; bv.u = *(const uint4*)&ws[nt * 16 + col][kt * 32 + g * 8];
        acc[nt] = __builtin_amdgcn_mfma_f32_16x16x32_f16(av.h, bv.h, acc[nt], 0, 0, 0);
      }
    }

    // ---- epilogue into split layout (gate = jt>>2 is uniform) ----
    const int gate = jt >> 2;
    const int ub   = (jt & 3) * 64;
#pragma unroll
    for (int nt = 0; nt < 4; ++nt) {
      const int u   = ub + nt * 16 + col;
      const float bvv = bi[jt * 64 + nt * 16 + col];
#pragma unroll
      for (int q = 0; q < 4; ++q) {
        const int rg = rbase + wv * 16 + g * 4 + q;   // D row = 4*(lane>>4)+q
        const _Float16 val = (_Float16)(acc[nt][q] + bvv);
        if (gate < 2) grz[((size_t)rg * 256 + u) * 2 + gate] = val;
        else          gn [(size_t)rg * 256 + u] = val;
      }
    }
    __syncthreads();   // ws reused next jt
  }
}

// ---------------- K2: serial GRU scan, chain-batched MFMA ------------------
// 512 thr = 8 waves. Wave w owns units 32w..32w+31 (B-frag tiles T=2m+us,
// R8/R9-proven). A rows = C chains (replication 16/C): chain = row>>SHIFT.
// D: col=lane&15, row=4*(lane>>4)+q.
template<int C, bool ENC>
__device__ __forceinline__ void gru_body(
    const int blk,
    const unsigned int* __restrict__ grzb,     // segment-adjusted (r,z) pairs
    const unsigned short* __restrict__ gnb,    // segment-adjusted n
    const float* __restrict__ W, const float* __restrict__ bh,
    float* __restrict__ obase,
    uint4* __restrict__ stage_q, unsigned short (&h_lds)[2][8][264])
{
  constexpr int SHIFT = (C == 2) ? 3 : 1;    // A/D row -> chain
  constexpr int NCH   = (C == 2) ? 1 : 2;    // chains per lane (gate phase)
  constexpr int LSEG  = ENC ? 1 : SEG_D;
  constexpr int LTOT  = WARM + LSEG;         // 97 or 101
  constexpr int GTOT  = ENC ? L_ENC : L_DEC;

  const int tid = threadIdx.x;
  const int lane = tid & 63, wave = tid >> 6;
  const int col = lane & 15, g = lane >> 4;

  // ---- stage W_hh as B-fragments (cross-thread launder; [j][t] layout) ----
  uint4 wq[48];
  {
    const int tp   = (tid + 1) & (NT - 1);
    const int wv_p = tp >> 6, ln_p = tp & 63;
    const int col_p = ln_p & 15, g_p = ln_p >> 4;
#pragma unroll
    for (int cch = 0; cch < 4; ++cch) {
#pragma unroll
      for (int j = 0; j < CH; ++j) {
        const int uu = cch * CH + j;      // 0..47
        const int Ti = uu >> 3;           // tile slot 0..5 (=2m+us)
        const int kt = uu & 7;            // k-tile 0..7
        const int m = Ti >> 1, us = Ti & 1;
        const int row = m * 256 + 32 * wv_p + 16 * us + col_p;
        const float* p = W + (size_t)row * H + 32 * kt + 8 * g_p;
        float4 f0 = *(const float4*)(p);
        float4 f1 = *(const float4*)(p + 4);
        HU a, b, c2, d;
        a.v[0]=(_Float16)f0.x;  a.v[1]=(_Float16)f0.y;
        b.v[0]=(_Float16)f0.z;  b.v[1]=(_Float16)f0.w;
        c2.v[0]=(_Float16)f1.x; c2.v[1]=(_Float16)f1.y;
        d.v[0]=(_Float16)f1.z;  d.v[1]=(_Float16)f1.w;
        uint4 pk; pk.x=a.u; pk.y=b.u; pk.z=c2.u; pk.w=d.u;
        stage_q[j * NT + tp] = pk;        // consecutive lanes -> consecutive 16B
      }
      __syncthreads();
#pragma unroll
      for (int j = 0; j < CH; ++j)
        wq[cch * CH + j] = stage_q[j * NT + tid];
      __syncthreads();
    }
  }

  const int u0 = 32 * wave + col, u1 = u0 + 16;
  const float bbr0 = bh[u0],       bbr1 = bh[u1];
  const float bbz0 = bh[H + u0],   bbz1 = bh[H + u1];
  const float bbn0 = bh[2*H + u0], bbn1 = bh[2*H + u1];

  int baseO[NCH]; int chO[NCH];
  if constexpr (ENC) {
    chO[0]   = g >> 1;                                  // D rows 0-7 / 8-15
    baseO[0] = 128 * (2 * blk + chO[0]) + 127 - WARM;   // >= 31, never negative
  } else {
    chO[0] = 2 * g; chO[1] = 2 * g + 1;                 // D rows 4g, 4g+2
    baseO[0] = SEG_D * (8 * blk + chO[0]) + SEG_D - LTOT;   // may be negative
    baseO[1] = SEG_D * (8 * blk + chO[1]) + SEG_D - LTOT;
  }

  { // zero both h buffers (incl. pad)
    unsigned int* hz = (unsigned int*)&h_lds[0][0][0];
#pragma unroll
    for (int z = 0; z < 5; ++z) { int idx = z * NT + tid; if (idx < 2112) hz[idx] = 0u; }
  }
  float h_old[NCH][2];
#pragma unroll
  for (int cc = 0; cc < NCH; ++cc) { h_old[cc][0] = 0.f; h_old[cc][1] = 0.f; }
  __syncthreads();

  // first-step gi (negative idx for DEC legally reads encoder region; masked)
  float gc[NCH][2][3];
#pragma unroll
  for (int cc = 0; cc < NCH; ++cc) {
    const unsigned int*   rp = grzb + (ptrdiff_t)baseO[cc] * 256;
    const unsigned short* np = gnb  + (ptrdiff_t)baseO[cc] * 256;
    HU z0, z1; z0.u = rp[u0]; z1.u = rp[u1];
    SH n0, n1; n0.s = np[u0]; n1.s = np[u1];
    gc[cc][0][0] = (float)z0.v[0]; gc[cc][0][1] = (float)z0.v[1]; gc[cc][0][2] = (float)n0.h;
    gc[cc][1][0] = (float)z1.v[0]; gc[cc][1][1] = (float)z1.v[1]; gc[cc][1][2] = (float)n1.h;
  }

  const int cA = col >> SHIFT;           // chain this lane's A-rows belong to
  for (int j = 0; j < LTOT; ++j) {
    // ---- issue next-step gi loads FIRST (hide under MFMA + gates) ----
    unsigned int   nrz[NCH][2];
    unsigned short nnn[NCH][2];
#pragma unroll
    for (int cc = 0; cc < NCH; ++cc) {
      int idx = baseO[cc] + j + 1;
      idx = idx < GTOT ? idx : GTOT - 1;          // upper clamp only
      const unsigned int*   rp = grzb + (ptrdiff_t)idx * 256;
      const unsigned short* np = gnb  + (ptrdiff_t)idx * 256;
      nrz[cc][0] = rp[u0]; nrz[cc][1] = rp[u1];
      nnn[cc][0] = np[u0]; nnn[cc][1] = np[u1];
    }

    // ---- MFMA matvec for all C chains at once ----
    const unsigned short* hb = &h_lds[j & 1][cA][0];
    f32x4 acc[6];
#pragma unroll
    for (int T = 0; T < 6; ++T) acc[T] = (f32x4){0.f, 0.f, 0.f, 0.f};
    __builtin_amdgcn_s_setprio(1);
#pragma unroll
    for (int kt = 0; kt < 8; ++kt) {
      U4H8 av; av.u = *(const uint4*)(hb + 32 * kt + 8 * g);
#pragma unroll
      for (int T = 0; T < 6; ++T) {
        U4H8 wv; wv.u = wq[T * 8 + kt];
        acc[T] = __builtin_amdgcn_mfma_f32_16x16x32_f16(av.h, wv.h, acc[T], 0, 0, 0);
      }
    }
    __builtin_amdgcn_s_setprio(0);

    // ---- extract this lane's D values (literal indices only) ----
    float dv[NCH][6];
    dv[0][0]=acc[0][0]; dv[0][1]=acc[1][0]; dv[0][2]=acc[2][0];
    dv[0][3]=acc[3][0]; dv[0][4]=acc[4][0]; dv[0][5]=acc[5][0];
    if constexpr (!ENC) {
      dv[1][0]=acc[0][2]; dv[1][1]=acc[1][2]; dv[1][2]=acc[2][2];
      dv[1][3]=acc[3][2]; dv[1][4]=acc[4][2]; dv[1][5]=acc[5][2];
    }

    // ---- gates, in-lane ----
    unsigned short* hwb = &h_lds[(j + 1) & 1][0][0];
#pragma unroll
    for (int cc = 0; cc < NCH; ++cc) {
      const int ic = baseO[cc] + j;
      _Float16* hw = (_Float16*)(hwb + chO[cc] * 264);
      {
        float r = fast_sigmoid(dv[cc][0] + bbr0 + gc[cc][0][0]);
        float z = fast_sigmoid(dv[cc][2] + bbz0 + gc[cc][0][1]);
        float n = 2.f * fast_sigmoid(2.f * (gc[cc][0][2] + r * (dv[cc][4] + bbn0))) - 1.f;
        float hnew = (1.f - z) * n + z * h_old[cc][0];
        if constexpr (!ENC) { if (ic < 0) hnew = 0.f; }
        h_old[cc][0] = hnew;
        if constexpr (ENC) {
          if ((g & 1) == 0) {
            hw[u0] = (_Float16)hnew;
            if (j == WARM) obase[(2 * blk + chO[0]) * H + u0] = hnew;
          }
        } else {
          hw[u0] = (_Float16)hnew;
          if (j >= WARM) obase[((ic & (B - 1)) * T_OUT + (ic >> 7)) * H + u0] = hnew;
        }
      }
      {
        float r = fast_sigmoid(dv[cc][1] + bbr1 + gc[cc][1][0]);
        float z = fast_sigmoid(dv[cc][3] + bbz1 + gc[cc][1][1]);
        float n = 2.f * fast_sigmoid(2.f * (gc[cc][1][2] + r * (dv[cc][5] + bbn1))) - 1.f;
        float hnew = (1.f - z) * n + z * h_old[cc][1];
        if constexpr (!ENC) { if (ic < 0) hnew = 0.f; }
        h_old[cc][1] = hnew;
        if constexpr (ENC) {
          if ((g & 1) == 0) {
            hw[u1] = (_Float16)hnew;
            if (j == WARM) obase[(2 * blk + chO[0]) * H + u1] = hnew;
          }
        } else {
          hw[u1] = (_Float16)hnew;
          if (j >= WARM) obase[((ic & (B - 1)) * T_OUT + (ic >> 7)) * H + u1] = hnew;
        }
      }
    }

    // ---- commit prefetched gi (single vmcnt wait lands here) ----
#pragma unroll
    for (int cc = 0; cc < NCH; ++cc) {
      HU z0, z1; z0.u = nrz[cc][0]; z1.u = nrz[cc][1];
      SH n0, n1; n0.s = nnn[cc][0]; n1.s = nnn[cc][1];
      gc[cc][0][0] = (float)z0.v[0]; gc[cc][0][1] = (float)z0.v[1]; gc[cc][0][2] = (float)n0.h;
      gc[cc][1][0] = (float)z1.v[0]; gc[cc][1][1] = (float)z1.v[1]; gc[cc][1][2] = (float)n1.h;
    }
    __syncthreads();   // publishes h_buf[(j+1)&1]
  }
}

__global__
__attribute__((amdgpu_flat_work_group_size(NT, NT)))
__attribute__((amdgpu_waves_per_eu(2, 2)))
void gru_serial(
    const _Float16* __restrict__ gi,
    const float* __restrict__ Whh_e, const float* __restrict__ bhh_e,
    const float* __restrict__ Whh_d, const float* __restrict__ bhh_d,
    float* __restrict__ out)
{
  __shared__ __align__(16) uint4 stage_q[NT * CH];             // 98304 B (>80KB lever)
  __shared__ __align__(16) unsigned short h_lds[2][8][264];    // 8448 B, dbuf
  const int blk = blockIdx.x;
  const unsigned int*   grz = (const unsigned int*)gi;
  const unsigned short* gn  = (const unsigned short*)(gi + GN_OFF);
  if (blk < NBLK_E)
    gru_body<2, true>(blk, grz, gn, Whh_e, bhh_e, out, stage_q, h_lds);
  else
    gru_body<8, false>(blk - NBLK_E, grz + (size_t)L_ENC * 256,
                       gn + (size_t)L_ENC * 256, Whh_d, bhh_d,
                       out + T_IN * H, stage_q, h_lds);
}

extern "C" void kernel_launch(void* const* d_in, const int* in_sizes, int n_in,
                              void* d_out, int out_size, void* d_ws, size_t ws_size,
                              hipStream_t stream) {
  (void)in_sizes; (void)n_in; (void)out_size; (void)ws_size;
  const float* x     = (const float*)d_in[0];
  const float* Wih_e = (const float*)d_in[1];
  const float* Whh_e = (const float*)d_in[2];
  const float* bih_e = (const float*)d_in[3];
  const float* bhh_e = (const float*)d_in[4];
  const float* Wih_d = (const float*)d_in[5];
  const float* Whh_d = (const float*)d_in[6];
  const float* bih_d = (const float*)d_in[7];
  const float* bhh_d = (const float*)d_in[8];
  float* out = (float*)d_out;
  _Float16* gi = (_Float16*)d_ws;    // needs 53,084,160 B

  gi_gemm<<<dim3((L_ENC + L_DEC) / 64), dim3(256), 0, stream>>>(
      x, Wih_e, bih_e, Wih_d, bih_d, gi);
  gru_serial<<<dim3(NBLK_E + NBLK_D), dim3(NT), 0, stream>>>(
      gi, Whh_e, bhh_e, Whh_d, bhh_d, out);
}